// Round 1
// baseline (11374.863 us; speedup 1.0000x reference)
//
#include <hip/hip_runtime.h>

// Window attention, fully fused: one workgroup per 7x7 window.
// B=32, H=W=56, C=256, nh=8, hd=32, ws=7 -> 2048 windows, 49 tokens each.
// Round 1: pure fp32 (correctness baseline). LDS ~127KB -> 1 block/CU.

__global__ __launch_bounds__(512) void winattn_f32(
    const float* __restrict__ x,
    const float* __restrict__ qkv_w,
    const float* __restrict__ qkv_b,
    const float* __restrict__ proj_w,
    const float* __restrict__ proj_b,
    const float* __restrict__ bias_table,
    float* __restrict__ out)
{
    constexpr int N2 = 49, NH = 8, HD = 32, C = 256;
    __shared__ float xw[N2][C];        // 50176 B, window input
    __shared__ float attn_out[N2][C];  // 50176 B, pre-proj attention output
    __shared__ float qh[N2][HD + 1];   // +1 pad: kill bank conflicts in QK^T
    __shared__ float kh[N2][HD + 1];
    __shared__ float vh[N2][HD + 1];
    __shared__ float sc[N2][N2 + 1];   // scores, padded

    const int wid = blockIdx.x;    // 0..2047
    const int b   = wid >> 6;      // batch
    const int wy  = (wid >> 3) & 7;
    const int wx  = wid & 7;
    const int tid = threadIdx.x;

    // ---- gather window into LDS (coalesced: consecutive tid -> consecutive c)
    const float* xbase = x + (size_t)b * (56 * 56) * C;
    for (int i = tid; i < N2 * C; i += 512) {
        int t = i >> 8, c = i & 255;
        int ti = t / 7, tj = t - ti * 7;
        xw[t][c] = xbase[((wy * 7 + ti) * 56 + (wx * 7 + tj)) * C + c];
    }
    __syncthreads();

    const float scale = 0.17677669529663687f;  // 32^-0.5

    for (int h = 0; h < NH; ++h) {
        // ---- QKV for this head: 3*49*32 = 4704 dots of length 256
        for (int i = tid; i < 3 * N2 * HD; i += 512) {
            int which = i / (N2 * HD);
            int rem = i - which * (N2 * HD);
            int t = rem >> 5, fl = rem & 31;
            int f = which * C + h * HD + fl;
            const float4* w4 = (const float4*)(qkv_w + (size_t)f * C);
            const float4* x4 = (const float4*)(&xw[t][0]);
            float acc = 0.f;
            #pragma unroll 8
            for (int c4 = 0; c4 < C / 4; ++c4) {
                float4 a = x4[c4], w = w4[c4];
                acc += a.x * w.x; acc += a.y * w.y;
                acc += a.z * w.z; acc += a.w * w.w;
            }
            acc += qkv_b[f];
            if (which == 0)      qh[t][fl] = acc;
            else if (which == 1) kh[t][fl] = acc;
            else                 vh[t][fl] = acc;
        }
        __syncthreads();

        // ---- scores: S[r][j] = scale * q[r].k[j] + bias[h][r][j]
        for (int i = tid; i < N2 * N2; i += 512) {
            int r = i / N2, j = i - r * N2;
            float acc = 0.f;
            #pragma unroll
            for (int d = 0; d < HD; ++d) acc += qh[r][d] * kh[j][d];
            int ri = r / 7, rj = r - ri * 7;
            int ji = j / 7, jj = j - ji * 7;
            int bidx = (ri - ji + 6) * 13 + (rj - jj + 6);
            sc[r][j] = acc * scale + bias_table[bidx * NH + h];
        }
        __syncthreads();

        // ---- softmax per row (49 rows; small, one thread each this round)
        if (tid < N2) {
            int r = tid;
            float m = -1e30f;
            for (int j = 0; j < N2; ++j) m = fmaxf(m, sc[r][j]);
            float s = 0.f;
            for (int j = 0; j < N2; ++j) { float e = __expf(sc[r][j] - m); sc[r][j] = e; s += e; }
            float inv = 1.f / s;
            for (int j = 0; j < N2; ++j) sc[r][j] *= inv;
        }
        __syncthreads();

        // ---- PV: out_h[r][d] = sum_j S[r][j] * v[j][d]
        for (int i = tid; i < N2 * HD; i += 512) {
            int r = i >> 5, d = i & 31;
            float acc = 0.f;
            #pragma unroll
            for (int j = 0; j < N2; ++j) acc += sc[r][j] * vh[j][d];
            attn_out[r][h * HD + d] = acc;
        }
        __syncthreads();  // qh/kh/vh reused next head
    }

    // ---- proj + scatter back to (B, H*W, C)
    float* obase = out + (size_t)b * (56 * 56) * C;
    for (int i = tid; i < N2 * C; i += 512) {
        int t = i >> 8, c = i & 255;
        const float4* w4 = (const float4*)(proj_w + (size_t)c * C);
        const float4* a4 = (const float4*)(&attn_out[t][0]);
        float acc = 0.f;
        #pragma unroll 8
        for (int k = 0; k < C / 4; ++k) {
            float4 a = a4[k], w = w4[k];
            acc += a.x * w.x; acc += a.y * w.y;
            acc += a.z * w.z; acc += a.w * w.w;
        }
        acc += proj_b[c];
        int ti = t / 7, tj = t - ti * 7;
        obase[((wy * 7 + ti) * 56 + (wx * 7 + tj)) * C + c] = acc;
    }
}

extern "C" void kernel_launch(void* const* d_in, const int* in_sizes, int n_in,
                              void* d_out, int out_size, void* d_ws, size_t ws_size,
                              hipStream_t stream) {
    const float* x          = (const float*)d_in[0];
    // d_in[1]=H, d_in[2]=W (ints, fixed 56 for this problem)
    const float* qkv_w      = (const float*)d_in[3];
    const float* qkv_b      = (const float*)d_in[4];
    const float* proj_w     = (const float*)d_in[5];
    const float* proj_b     = (const float*)d_in[6];
    const float* bias_table = (const float*)d_in[7];
    float* out = (float*)d_out;

    hipLaunchKernelGGL(winattn_f32, dim3(2048), dim3(512), 0, stream,
                       x, qkv_w, qkv_b, proj_w, proj_b, bias_table, out);
}

// Round 3
// 208.125 us; speedup vs baseline: 54.6539x; 54.6539x over previous
//
#include <hip/hip_runtime.h>

// Window attention on MFMA (fp16 in, fp32 accum). One WG (512 thr = 8 waves)
// per 7x7 window; wave w = head w. Stages:
//   0) pre-kernel: qkv_w/proj_w fp32 -> fp16 into d_ws
//   1) X window -> LDS fp16 [64][256], XOR-swizzled rows (pads zeroed)
//   2) per-head QKV GEMM (M=64,N=96,K=256), write Q*scale / K / V^T to LDS
//   3) S^T = K*Q^T (swapped: C-layout col = q), bias+mask+softmax in-register
//   4) O^T = V^T * P^T, P^T B-frags built via shfl (no P in LDS)
//   5) O -> LDS (aliases X), proj GEMM (M=64,N=32/wave,K=256), scatter out
// LDS: 32768 (X/O) + 5408 (bias) + 8*14848 (Q,K,Vt per head) = 156960 B.

typedef _Float16 half_t;
typedef _Float16 half8  __attribute__((ext_vector_type(8)));
typedef float    f32x4  __attribute__((ext_vector_type(4)));

#define MFMA16(a, b, c) __builtin_amdgcn_mfma_f32_16x16x32_f16((a), (b), (c), 0, 0, 0)

__global__ __launch_bounds__(256) void convert_w(const float* __restrict__ qkv_w,
                                                 const float* __restrict__ proj_w,
                                                 half_t* __restrict__ w16) {
    int i = blockIdx.x * 256 + threadIdx.x;           // grid covers exactly 262144
    if (i < 768 * 256) w16[i] = (half_t)qkv_w[i];
    else               w16[i] = (half_t)proj_w[i - 768 * 256];
}

__global__ __launch_bounds__(512, 2) void winattn_mfma(
    const float* __restrict__ x,
    const float* __restrict__ qkv_b,
    const float* __restrict__ proj_b,
    const float* __restrict__ bias_table,
    const half_t* __restrict__ w16,
    float* __restrict__ out)
{
    constexpr int C = 256;
    __shared__ __align__(16) char smem[156960];
    float* bias_s = (float*)(smem + 32768);           // [169][8] fp32

    const int tid  = threadIdx.x;
    const int wave = tid >> 6;
    const int lane = tid & 63;
    const int g    = lane >> 4;                       // 0..3 (16-lane group)
    const int l15  = lane & 15;

    const int wid = blockIdx.x;
    const int b   = wid >> 6;
    const int wy  = (wid >> 3) & 7;
    const int wx  = wid & 7;
    const float* xbase = x   + (size_t)b * 3136 * C;
    float*       obase = out + (size_t)b * 3136 * C;

    // ---- stage bias table
    for (int i = tid; i < 169 * 8; i += 512) bias_s[i] = bias_table[i];

    // ---- stage X fp32->fp16, rows 49..63 zero. Row swizzle: byte ^= (row&7)<<4
    for (int i = tid; i < 64 * 32; i += 512) {
        int row = i >> 5, ch = i & 31;
        char* dst = smem + row * 512 + ((ch * 16) ^ ((row & 7) << 4));
        if (row < 49) {
            int ti = row / 7, tj = row % 7;
            const float* src = xbase + ((wy * 7 + ti) * 56 + (wx * 7 + tj)) * C + ch * 8;
            float4 f0 = ((const float4*)src)[0];
            float4 f1 = ((const float4*)src)[1];
            half8 v = { (half_t)f0.x, (half_t)f0.y, (half_t)f0.z, (half_t)f0.w,
                        (half_t)f1.x, (half_t)f1.y, (half_t)f1.z, (half_t)f1.w };
            *(half8*)dst = v;
        } else {
            half8 v = { (half_t)0, (half_t)0, (half_t)0, (half_t)0,
                        (half_t)0, (half_t)0, (half_t)0, (half_t)0 };
            *(half8*)dst = v;
        }
    }
    __syncthreads();

    // ---- per-head LDS tiles
    const int h = wave;
    half_t* q_s  = (half_t*)(smem + 38176 + h * 14848);   // [64][40] (Q*scale)
    half_t* k_s  = q_s + 64 * 40;                         // [64][40]
    half_t* vt_s = k_s + 64 * 40;                         // [32][72] = V^T

    const f32x4 fz = {0.f, 0.f, 0.f, 0.f};

    // ---- QKV GEMM: M=64 tok, N=96 (Q0 Q1 K0 K1 V0 V1), K=256
    f32x4 acc[4][6];
    #pragma unroll
    for (int mt = 0; mt < 4; ++mt)
        #pragma unroll
        for (int nt = 0; nt < 6; ++nt) acc[mt][nt] = fz;

    #pragma unroll
    for (int s = 0; s < 8; ++s) {
        half8 af[4], bf[6];
        #pragma unroll
        for (int mt = 0; mt < 4; ++mt) {
            int row = mt * 16 + l15;
            af[mt] = *(const half8*)(smem + row * 512 + ((s * 64 + g * 16) ^ ((row & 7) << 4)));
        }
        #pragma unroll
        for (int nt = 0; nt < 6; ++nt) {
            int f = (nt >> 1) * 256 + h * 32 + (nt & 1) * 16 + l15;   // qkv_w row
            bf[nt] = *(const half8*)(w16 + (size_t)f * 256 + s * 32 + g * 8);
        }
        #pragma unroll
        for (int mt = 0; mt < 4; ++mt)
            #pragma unroll
            for (int nt = 0; nt < 6; ++nt)
                acc[mt][nt] = MFMA16(af[mt], bf[nt], acc[mt][nt]);
    }

    // ---- C-write: Q (scaled) / K row-major [64][40], V transposed [32][72]
    const float SCALE = 0.17677669529663687f;   // 32^-0.5
    #pragma unroll
    for (int nt = 0; nt < 6; ++nt) {
        int which = nt >> 1;                    // 0=Q 1=K 2=V
        int dl = (nt & 1) * 16 + l15;           // 0..31 within head
        float bb = qkv_b[which * 256 + h * 32 + dl];
        #pragma unroll
        for (int mt = 0; mt < 4; ++mt)
            #pragma unroll
            for (int r = 0; r < 4; ++r) {
                int tok = mt * 16 + g * 4 + r;
                float v = acc[mt][nt][r] + bb;
                if (which == 0)      q_s[tok * 40 + dl]  = (half_t)(v * SCALE);
                else if (which == 1) k_s[tok * 40 + dl]  = (half_t)v;
                else                 vt_s[dl * 72 + tok] = (half_t)v;
            }
    }
    __syncthreads();    // all waves done reading X -> O region reusable

    // ---- S^T = K * Q^T : M=64 k-tok, N=64 q, K=32 (one MFMA k-step)
    f32x4 st[4][4];
    #pragma unroll
    for (int mt = 0; mt < 4; ++mt)
        #pragma unroll
        for (int nt = 0; nt < 4; ++nt) st[mt][nt] = fz;
    {
        half8 ak[4], bq[4];
        #pragma unroll
        for (int mt = 0; mt < 4; ++mt)
            ak[mt] = *(const half8*)(k_s + (mt * 16 + l15) * 40 + g * 8);
        #pragma unroll
        for (int nt = 0; nt < 4; ++nt)
            bq[nt] = *(const half8*)(q_s + (nt * 16 + l15) * 40 + g * 8);
        #pragma unroll
        for (int mt = 0; mt < 4; ++mt)
            #pragma unroll
            for (int nt = 0; nt < 4; ++nt)
                st[mt][nt] = MFMA16(ak[mt], bq[nt], st[mt][nt]);
    }

    // ---- bias + mask (k>=49 -> -inf) + softmax over k (rows of S^T)
    int qcode[4];
    #pragma unroll
    for (int nt = 0; nt < 4; ++nt) {
        int q = nt * 16 + l15; if (q > 48) q = 48;
        qcode[nt] = (q / 7) * 13 + (q % 7) + 84;
    }
    float mx[4] = {-1e30f, -1e30f, -1e30f, -1e30f};
    #pragma unroll
    for (int mt = 0; mt < 4; ++mt)
        #pragma unroll
        for (int r = 0; r < 4; ++r) {
            int k = mt * 16 + g * 4 + r;
            bool valid = (k < 49);
            int kc = valid ? ((k / 7) * 13 + (k % 7)) : 0;
            #pragma unroll
            for (int nt = 0; nt < 4; ++nt) {
                float v = valid ? (st[mt][nt][r] + bias_s[(qcode[nt] - kc) * 8 + h])
                                : -1e30f;
                st[mt][nt][r] = v;
                mx[nt] = fmaxf(mx[nt], v);
            }
        }
    #pragma unroll
    for (int nt = 0; nt < 4; ++nt) {
        mx[nt] = fmaxf(mx[nt], __shfl_xor(mx[nt], 16, 64));
        mx[nt] = fmaxf(mx[nt], __shfl_xor(mx[nt], 32, 64));
    }
    float sm[4] = {0.f, 0.f, 0.f, 0.f};
    #pragma unroll
    for (int mt = 0; mt < 4; ++mt)
        #pragma unroll
        for (int nt = 0; nt < 4; ++nt)
            #pragma unroll
            for (int r = 0; r < 4; ++r) {
                float e = __expf(st[mt][nt][r] - mx[nt]);
                st[mt][nt][r] = e;
                sm[nt] += e;
            }
    float inv[4];
    #pragma unroll
    for (int nt = 0; nt < 4; ++nt) {
        float ssum = sm[nt] + __shfl_xor(sm[nt], 16, 64);
        ssum += __shfl_xor(ssum, 32, 64);
        inv[nt] = 1.0f / ssum;              // folded into O-write
    }

    // ---- pack P^T (unnormalized) to f16 pairs: pk[mt][nt] = {regs01, regs23}
    unsigned int pk[4][4][2];
    #pragma unroll
    for (int mt = 0; mt < 4; ++mt)
        #pragma unroll
        for (int nt = 0; nt < 4; ++nt) {
            pk[mt][nt][0] = __builtin_bit_cast(unsigned int,
                __builtin_amdgcn_cvt_pkrtz(st[mt][nt][0], st[mt][nt][1]));
            pk[mt][nt][1] = __builtin_bit_cast(unsigned int,
                __builtin_amdgcn_cvt_pkrtz(st[mt][nt][2], st[mt][nt][3]));
        }

    // ---- O^T = V^T * P^T : M=32 d, N=64 q, K=64 tok (2 k-steps)
    // B-frag lane l needs P^T[s*32+8g+j][q=l15]; source C-layout lane (gsrc<<4)|l15,
    // mtile 2s+(g>>1), with gsrcA=2*(g&1) for j0..3, gsrcB=gsrcA+1 for j4..7.
    f32x4 ot[2][4];
    #pragma unroll
    for (int md = 0; md < 2; ++md)
        #pragma unroll
        for (int nt = 0; nt < 4; ++nt) ot[md][nt] = fz;

    const int srcA = (g & 1) * 32 + l15;
    const int srcB = srcA + 16;
    const bool lowHalf = (g < 2);
    #pragma unroll
    for (int s = 0; s < 2; ++s) {
        half8 av[2];
        #pragma unroll
        for (int md = 0; md < 2; ++md)
            av[md] = *(const half8*)(vt_s + (md * 16 + l15) * 72 + s * 32 + g * 8);
        #pragma unroll
        for (int nt = 0; nt < 4; ++nt) {
            unsigned int a0 = __shfl(pk[2 * s][nt][0], srcA, 64);
            unsigned int a1 = __shfl(pk[2 * s][nt][1], srcA, 64);
            unsigned int a2 = __shfl(pk[2 * s][nt][0], srcB, 64);
            unsigned int a3 = __shfl(pk[2 * s][nt][1], srcB, 64);
            unsigned int b0 = __shfl(pk[2 * s + 1][nt][0], srcA, 64);
            unsigned int b1 = __shfl(pk[2 * s + 1][nt][1], srcA, 64);
            unsigned int b2 = __shfl(pk[2 * s + 1][nt][0], srcB, 64);
            unsigned int b3 = __shfl(pk[2 * s + 1][nt][1], srcB, 64);
            uint4 fr;
            fr.x = lowHalf ? a0 : b0;
            fr.y = lowHalf ? a1 : b1;
            fr.z = lowHalf ? a2 : b2;
            fr.w = lowHalf ? a3 : b3;
            half8 pb = __builtin_bit_cast(half8, fr);
            #pragma unroll
            for (int md = 0; md < 2; ++md)
                ot[md][nt] = MFMA16(av[md], pb, ot[md][nt]);
        }
    }

    // ---- O write (f16, normalized) into X-aliased swizzled tile
    #pragma unroll
    for (int md = 0; md < 2; ++md)
        #pragma unroll
        for (int nt = 0; nt < 4; ++nt)
            #pragma unroll
            for (int r = 0; r < 4; ++r) {
                int q = nt * 16 + l15;
                int d = h * 32 + md * 16 + g * 4 + r;
                *(half_t*)(smem + q * 512 + ((d * 2) ^ ((q & 7) << 4))) =
                    (half_t)(ot[md][nt][r] * inv[nt]);
            }
    __syncthreads();

    // ---- proj: wave computes features [wave*32, wave*32+32), M=64, K=256
    const half_t* pw = w16 + 768 * 256;
    f32x4 pa[4][2];
    #pragma unroll
    for (int mt = 0; mt < 4; ++mt)
        #pragma unroll
        for (int nt = 0; nt < 2; ++nt) pa[mt][nt] = fz;
    #pragma unroll
    for (int s = 0; s < 8; ++s) {
        half8 af[4], bf[2];
        #pragma unroll
        for (int mt = 0; mt < 4; ++mt) {
            int row = mt * 16 + l15;
            af[mt] = *(const half8*)(smem + row * 512 + ((s * 64 + g * 16) ^ ((row & 7) << 4)));
        }
        #pragma unroll
        for (int nt = 0; nt < 2; ++nt) {
            int f = wave * 32 + nt * 16 + l15;
            bf[nt] = *(const half8*)(pw + (size_t)f * 256 + s * 32 + g * 8);
        }
        #pragma unroll
        for (int mt = 0; mt < 4; ++mt)
            #pragma unroll
            for (int nt = 0; nt < 2; ++nt)
                pa[mt][nt] = MFMA16(af[mt], bf[nt], pa[mt][nt]);
    }
    // ---- epilogue: +proj_b, scatter (only tok<49)
    #pragma unroll
    for (int nt = 0; nt < 2; ++nt) {
        int f = wave * 32 + nt * 16 + l15;
        float pb = proj_b[f];
        #pragma unroll
        for (int mt = 0; mt < 4; ++mt)
            #pragma unroll
            for (int r = 0; r < 4; ++r) {
                int tok = mt * 16 + g * 4 + r;
                if (tok < 49) {
                    int ti = tok / 7, tj = tok % 7;
                    obase[((wy * 7 + ti) * 56 + (wx * 7 + tj)) * C + f] =
                        pa[mt][nt][r] + pb;
                }
            }
    }
}

extern "C" void kernel_launch(void* const* d_in, const int* in_sizes, int n_in,
                              void* d_out, int out_size, void* d_ws, size_t ws_size,
                              hipStream_t stream) {
    const float* x          = (const float*)d_in[0];
    const float* qkv_w      = (const float*)d_in[3];
    const float* qkv_b      = (const float*)d_in[4];
    const float* proj_w     = (const float*)d_in[5];
    const float* proj_b     = (const float*)d_in[6];
    const float* bias_table = (const float*)d_in[7];
    float* out = (float*)d_out;
    half_t* w16 = (half_t*)d_ws;   // 768*256 + 256*256 halfs = 524288 B

    hipLaunchKernelGGL(convert_w, dim3(1024), dim3(256), 0, stream,
                       qkv_w, proj_w, w16);
    hipLaunchKernelGGL(winattn_mfma, dim3(2048), dim3(512), 0, stream,
                       x, qkv_b, proj_b, bias_table, w16, out);
}

// Round 4
// 191.735 us; speedup vs baseline: 59.3258x; 1.0855x over previous
//
#include <hip/hip_runtime.h>

// Window attention, register-resident MFMA version.
// One WG (512 thr = 8 waves) per 7x7 window; wave = head.
// Key idea: compute Q^T,K^T (A=W rows, B=X^T) and V (A=X rows, B=Wv) so that
// S^T = K*Q^T and O = P*V operand fragments are built from the previous
// stage's MFMA C-layout accumulators with a uniform 4-lane shfl permutation
// (srcA/srcB + dual-tile select). No Q/K/V LDS round-trip at all.
// LDS = X/O tile 32KB + bias 5.4KB = 38176 B -> 2 blocks/CU at VGPR<=128.

typedef _Float16 half_t;
typedef _Float16 half8 __attribute__((ext_vector_type(8)));
typedef float    f32x4 __attribute__((ext_vector_type(4)));

#define MFMA16(a, b, c) __builtin_amdgcn_mfma_f32_16x16x32_f16((a), (b), (c), 0, 0, 0)

__global__ __launch_bounds__(256) void convert_w(const float* __restrict__ qkv_w,
                                                 const float* __restrict__ proj_w,
                                                 half_t* __restrict__ w16) {
    int i = blockIdx.x * 256 + threadIdx.x;           // grid covers exactly 262144
    if (i < 768 * 256) w16[i] = (half_t)qkv_w[i];
    else               w16[i] = (half_t)proj_w[i - 768 * 256];
}

// pack two f32 -> one dword of 2 fp16 (RNE)
static __device__ __forceinline__ unsigned pk2(float a, float b) {
    union { half_t h[2]; unsigned u; } t;
    t.h[0] = (half_t)a; t.h[1] = (half_t)b; return t.u;
}

// Build an A/B-frag (8 fp16) from a packed C-layout tile pair.
// Element wanted at lane (g,l): M[l][8g+j] where M = (C')^T and C' tiles are
// pk0 (rows 0..15) / pk1 (rows 16..31); row u=8(g&1)+j lives at src lane
// ((2(g&1)+(j>>2))&3)*16+l, dword (j>>1)&1; tile chosen by g>>1.
static __device__ __forceinline__ half8 frag_pk(unsigned p0l, unsigned p0h,
                                                unsigned p1l, unsigned p1h,
                                                int srcA, int srcB, bool lo) {
    unsigned a0 = __shfl(p0l, srcA, 64), a1 = __shfl(p0h, srcA, 64);
    unsigned a2 = __shfl(p0l, srcB, 64), a3 = __shfl(p0h, srcB, 64);
    unsigned b0 = __shfl(p1l, srcA, 64), b1 = __shfl(p1h, srcA, 64);
    unsigned b2 = __shfl(p1l, srcB, 64), b3 = __shfl(p1h, srcB, 64);
    uint4 fr;
    fr.x = lo ? a0 : b0; fr.y = lo ? a1 : b1;
    fr.z = lo ? a2 : b2; fr.w = lo ? a3 : b3;
    return __builtin_bit_cast(half8, fr);
}

__global__ __launch_bounds__(512, 4) void winattn_mfma(
    const float* __restrict__ x,
    const float* __restrict__ qkv_b,
    const float* __restrict__ proj_b,
    const float* __restrict__ bias_table,
    const half_t* __restrict__ w16,
    float* __restrict__ out)
{
    constexpr int C = 256;
    __shared__ __align__(16) char smem[38176];
    float* bias_s = (float*)(smem + 32768);           // [169][8] fp32

    const int tid  = threadIdx.x;
    const int wave = tid >> 6;
    const int lane = tid & 63;
    const int g    = lane >> 4;
    const int l15  = lane & 15;

    const int wid = blockIdx.x;
    const int b   = wid >> 6;
    const int wy  = (wid >> 3) & 7;
    const int wx  = wid & 7;
    const float* xbase = x   + (size_t)b * 3136 * C;
    float*       obase = out + (size_t)b * 3136 * C;

    for (int i = tid; i < 169 * 8; i += 512) bias_s[i] = bias_table[i];

    // ---- stage X fp32->fp16 [64][256], rows 49..63 zero, swizzle byte^=(row&7)<<4
    for (int i = tid; i < 64 * 32; i += 512) {
        int row = i >> 5, ch = i & 31;
        char* dst = smem + row * 512 + ((ch * 16) ^ ((row & 7) << 4));
        if (row < 49) {
            int ti = row / 7, tj = row % 7;
            const float* src = xbase + ((wy * 7 + ti) * 56 + (wx * 7 + tj)) * C + ch * 8;
            float4 f0 = ((const float4*)src)[0];
            float4 f1 = ((const float4*)src)[1];
            half8 v = { (half_t)f0.x, (half_t)f0.y, (half_t)f0.z, (half_t)f0.w,
                        (half_t)f1.x, (half_t)f1.y, (half_t)f1.z, (half_t)f1.w };
            *(half8*)dst = v;
        } else {
            half8 v = { (half_t)0, (half_t)0, (half_t)0, (half_t)0,
                        (half_t)0, (half_t)0, (half_t)0, (half_t)0 };
            *(half8*)dst = v;
        }
    }
    __syncthreads();

    const int h = wave;
    const int srcA = (g & 1) * 32 + l15;
    const int srcB = srcA + 16;
    const bool lo = (g < 2);
    const f32x4 fz = {0.f, 0.f, 0.f, 0.f};
    const float SCALE = 0.17677669529663687f;   // 32^-0.5

    // ================= pass 1: Q^T,K^T = W*X^T  (M=d 2 tiles, N=t 4 tiles)
    f32x4 qacc[2][4], kacc[2][4];
    #pragma unroll
    for (int mt = 0; mt < 2; ++mt)
        #pragma unroll
        for (int nt = 0; nt < 4; ++nt) { qacc[mt][nt] = fz; kacc[mt][nt] = fz; }

    #pragma unroll
    for (int s = 0; s < 8; ++s) {
        half8 xf[4];
        #pragma unroll
        for (int nt = 0; nt < 4; ++nt) {
            int row = nt * 16 + l15;
            xf[nt] = *(const half8*)(smem + row * 512 + ((s * 64 + g * 16) ^ ((row & 7) << 4)));
        }
        half8 wqf[2], wkf[2];
        #pragma unroll
        for (int mt = 0; mt < 2; ++mt) {
            int d = h * 32 + mt * 16 + l15;
            wqf[mt] = *(const half8*)(w16 + (size_t)d * 256 + s * 32 + g * 8);
            wkf[mt] = *(const half8*)(w16 + (size_t)(256 + d) * 256 + s * 32 + g * 8);
        }
        #pragma unroll
        for (int mt = 0; mt < 2; ++mt)
            #pragma unroll
            for (int nt = 0; nt < 4; ++nt) {
                qacc[mt][nt] = MFMA16(wqf[mt], xf[nt], qacc[mt][nt]);
                kacc[mt][nt] = MFMA16(wkf[mt], xf[nt], kacc[mt][nt]);
            }
    }

    // pack Q^T (bias+scale) / K^T (bias) to fp16 dwords
    unsigned pkq[2][4][2], pkk[2][4][2];
    #pragma unroll
    for (int mt = 0; mt < 2; ++mt) {
        float bq[4], bk[4];
        #pragma unroll
        for (int r = 0; r < 4; ++r) {
            int d = h * 32 + mt * 16 + 4 * g + r;
            bq[r] = qkv_b[d];
            bk[r] = qkv_b[256 + d];
        }
        #pragma unroll
        for (int nt = 0; nt < 4; ++nt) {
            pkq[mt][nt][0] = pk2((qacc[mt][nt][0] + bq[0]) * SCALE,
                                 (qacc[mt][nt][1] + bq[1]) * SCALE);
            pkq[mt][nt][1] = pk2((qacc[mt][nt][2] + bq[2]) * SCALE,
                                 (qacc[mt][nt][3] + bq[3]) * SCALE);
            pkk[mt][nt][0] = pk2(kacc[mt][nt][0] + bk[0], kacc[mt][nt][1] + bk[1]);
            pkk[mt][nt][1] = pk2(kacc[mt][nt][2] + bk[2], kacc[mt][nt][3] + bk[3]);
        }
    }

    // ================= pass 2: S^T = K * Q^T  (M=k 4 tiles, N=q 4 tiles, K=32)
    half8 bqf[4];
    #pragma unroll
    for (int nt = 0; nt < 4; ++nt)
        bqf[nt] = frag_pk(pkq[0][nt][0], pkq[0][nt][1],
                          pkq[1][nt][0], pkq[1][nt][1], srcA, srcB, lo);
    f32x4 st[4][4];
    #pragma unroll
    for (int mt = 0; mt < 4; ++mt)
        #pragma unroll
        for (int nt = 0; nt < 4; ++nt) st[mt][nt] = fz;
    #pragma unroll
    for (int mt = 0; mt < 4; ++mt) {
        half8 ak = frag_pk(pkk[0][mt][0], pkk[0][mt][1],
                           pkk[1][mt][0], pkk[1][mt][1], srcA, srcB, lo);
        #pragma unroll
        for (int nt = 0; nt < 4; ++nt)
            st[mt][nt] = MFMA16(ak, bqf[nt], st[mt][nt]);
    }

    // ---- bias + mask + softmax over k (rows of S^T); layout identical to R3
    int qcode[4];
    #pragma unroll
    for (int nt = 0; nt < 4; ++nt) {
        int q = nt * 16 + l15; if (q > 48) q = 48;
        qcode[nt] = (q / 7) * 13 + (q % 7) + 84;
    }
    float mx[4] = {-1e30f, -1e30f, -1e30f, -1e30f};
    #pragma unroll
    for (int mt = 0; mt < 4; ++mt)
        #pragma unroll
        for (int r = 0; r < 4; ++r) {
            int k = mt * 16 + g * 4 + r;
            bool valid = (k < 49);
            int kc = valid ? ((k / 7) * 13 + (k % 7)) : 0;
            #pragma unroll
            for (int nt = 0; nt < 4; ++nt) {
                float v = valid ? (st[mt][nt][r] + bias_s[(qcode[nt] - kc) * 8 + h])
                                : -1e30f;
                st[mt][nt][r] = v;
                mx[nt] = fmaxf(mx[nt], v);
            }
        }
    #pragma unroll
    for (int nt = 0; nt < 4; ++nt) {
        mx[nt] = fmaxf(mx[nt], __shfl_xor(mx[nt], 16, 64));
        mx[nt] = fmaxf(mx[nt], __shfl_xor(mx[nt], 32, 64));
    }
    float sm[4] = {0.f, 0.f, 0.f, 0.f};
    #pragma unroll
    for (int mt = 0; mt < 4; ++mt)
        #pragma unroll
        for (int nt = 0; nt < 4; ++nt)
            #pragma unroll
            for (int r = 0; r < 4; ++r) {
                float e = __expf(st[mt][nt][r] - mx[nt]);
                st[mt][nt][r] = e;
                sm[nt] += e;
            }
    float inv[4];
    #pragma unroll
    for (int nt = 0; nt < 4; ++nt) {
        float ssum = sm[nt] + __shfl_xor(sm[nt], 16, 64);
        ssum += __shfl_xor(ssum, 32, 64);
        inv[nt] = 1.0f / ssum;
    }
    // pack normalized P (cols q get inv[nt], uniform across groups)
    unsigned pkp[4][4][2];
    #pragma unroll
    for (int mt = 0; mt < 4; ++mt)
        #pragma unroll
        for (int nt = 0; nt < 4; ++nt) {
            pkp[mt][nt][0] = pk2(st[mt][nt][0] * inv[nt], st[mt][nt][1] * inv[nt]);
            pkp[mt][nt][1] = pk2(st[mt][nt][2] * inv[nt], st[mt][nt][3] * inv[nt]);
        }

    // ================= pass 3: V = X * Wv^T  (M=t 4 tiles, N=d 2 tiles)
    f32x4 vacc[4][2];
    #pragma unroll
    for (int mt = 0; mt < 4; ++mt)
        #pragma unroll
        for (int nd = 0; nd < 2; ++nd) vacc[mt][nd] = fz;
    #pragma unroll
    for (int s = 0; s < 8; ++s) {
        half8 xf[4];
        #pragma unroll
        for (int mt = 0; mt < 4; ++mt) {
            int row = mt * 16 + l15;
            xf[mt] = *(const half8*)(smem + row * 512 + ((s * 64 + g * 16) ^ ((row & 7) << 4)));
        }
        half8 wvf[2];
        #pragma unroll
        for (int nd = 0; nd < 2; ++nd) {
            int d = 512 + h * 32 + nd * 16 + l15;
            wvf[nd] = *(const half8*)(w16 + (size_t)d * 256 + s * 32 + g * 8);
        }
        #pragma unroll
        for (int mt = 0; mt < 4; ++mt)
            #pragma unroll
            for (int nd = 0; nd < 2; ++nd)
                vacc[mt][nd] = MFMA16(xf[mt], wvf[nd], vacc[mt][nd]);
    }
    unsigned pkv[4][2][2];
    #pragma unroll
    for (int nd = 0; nd < 2; ++nd) {
        float bv = qkv_b[512 + h * 32 + nd * 16 + l15];
        #pragma unroll
        for (int mt = 0; mt < 4; ++mt) {
            pkv[mt][nd][0] = pk2(vacc[mt][nd][0] + bv, vacc[mt][nd][1] + bv);
            pkv[mt][nd][1] = pk2(vacc[mt][nd][2] + bv, vacc[mt][nd][3] + bv);
        }
    }

    // ================= pass 4: O = P * V  (M=q 4 tiles, N=d 2 tiles, K=64)
    f32x4 oacc[4][2];
    #pragma unroll
    for (int mq = 0; mq < 4; ++mq)
        #pragma unroll
        for (int nd = 0; nd < 2; ++nd) oacc[mq][nd] = fz;
    #pragma unroll
    for (int ks = 0; ks < 2; ++ks) {
        half8 bvf[2];
        #pragma unroll
        for (int nd = 0; nd < 2; ++nd)
            bvf[nd] = frag_pk(pkv[2 * ks][nd][0], pkv[2 * ks][nd][1],
                              pkv[2 * ks + 1][nd][0], pkv[2 * ks + 1][nd][1],
                              srcA, srcB, lo);
        #pragma unroll
        for (int mq = 0; mq < 4; ++mq) {
            half8 ap = frag_pk(pkp[2 * ks][mq][0], pkp[2 * ks][mq][1],
                               pkp[2 * ks + 1][mq][0], pkp[2 * ks + 1][mq][1],
                               srcA, srcB, lo);
            #pragma unroll
            for (int nd = 0; nd < 2; ++nd)
                oacc[mq][nd] = MFMA16(ap, bvf[nd], oacc[mq][nd]);
        }
    }

    // all waves must be done reading X before O overwrites the tile
    __syncthreads();

    // ---- O write (fp16, normalized) into X-aliased swizzled tile
    #pragma unroll
    for (int mq = 0; mq < 4; ++mq)
        #pragma unroll
        for (int nd = 0; nd < 2; ++nd)
            #pragma unroll
            for (int r = 0; r < 4; ++r) {
                int q = mq * 16 + 4 * g + r;
                int d = h * 32 + nd * 16 + l15;
                *(half_t*)(smem + q * 512 + ((d * 2) ^ ((q & 7) << 4))) =
                    (half_t)oacc[mq][nd][r];
            }
    __syncthreads();

    // ================= proj: wave computes features [wave*32, +32), K=256
    const half_t* pw = w16 + 768 * 256;
    f32x4 pa[4][2];
    #pragma unroll
    for (int mt = 0; mt < 4; ++mt)
        #pragma unroll
        for (int nt = 0; nt < 2; ++nt) pa[mt][nt] = fz;
    #pragma unroll
    for (int s = 0; s < 8; ++s) {
        half8 af[4], bf[2];
        #pragma unroll
        for (int mt = 0; mt < 4; ++mt) {
            int row = mt * 16 + l15;
            af[mt] = *(const half8*)(smem + row * 512 + ((s * 64 + g * 16) ^ ((row & 7) << 4)));
        }
        #pragma unroll
        for (int nt = 0; nt < 2; ++nt) {
            int f = wave * 32 + nt * 16 + l15;
            bf[nt] = *(const half8*)(pw + (size_t)f * 256 + s * 32 + g * 8);
        }
        #pragma unroll
        for (int mt = 0; mt < 4; ++mt)
            #pragma unroll
            for (int nt = 0; nt < 2; ++nt)
                pa[mt][nt] = MFMA16(af[mt], bf[nt], pa[mt][nt]);
    }
    #pragma unroll
    for (int nt = 0; nt < 2; ++nt) {
        int f = wave * 32 + nt * 16 + l15;
        float pb = proj_b[f];
        #pragma unroll
        for (int mt = 0; mt < 4; ++mt)
            #pragma unroll
            for (int r = 0; r < 4; ++r) {
                int tok = mt * 16 + g * 4 + r;
                if (tok < 49) {
                    int ti = tok / 7, tj = tok % 7;
                    obase[((wy * 7 + ti) * 56 + (wx * 7 + tj)) * C + f] =
                        pa[mt][nt][r] + pb;
                }
            }
    }
}

extern "C" void kernel_launch(void* const* d_in, const int* in_sizes, int n_in,
                              void* d_out, int out_size, void* d_ws, size_t ws_size,
                              hipStream_t stream) {
    const float* x          = (const float*)d_in[0];
    const float* qkv_w      = (const float*)d_in[3];
    const float* qkv_b      = (const float*)d_in[4];
    const float* proj_w     = (const float*)d_in[5];
    const float* proj_b     = (const float*)d_in[6];
    const float* bias_table = (const float*)d_in[7];
    float* out = (float*)d_out;
    half_t* w16 = (half_t*)d_ws;   // 1024*256 halfs = 524288 B

    hipLaunchKernelGGL(convert_w, dim3(1024), dim3(256), 0, stream,
                       qkv_w, proj_w, w16);
    hipLaunchKernelGGL(winattn_mfma, dim3(2048), dim3(512), 0, stream,
                       x, qkv_b, proj_b, bias_table, w16, out);
}